// Round 3
// baseline (421.805 us; speedup 1.0000x reference)
//
#include <hip/hip_runtime.h>
#include <stdint.h>

// irreps linear: 4 paths, out[v,i] = (1/64) * sum_u x[u,i] * w[u,v]
// mul = 4096 all paths, D in {1,3,5,7}. All tensors f32.
//
// NO workspace (round-2 post-timing corruption traced to d_ws overflow):
// every output fully reduced inside one block.
//   grid = 256 blocks (= 4 paths x 64 v-tiles of 64), 1024 threads (16 waves).
//   lane (t&63) -> v within tile  => per-u wave load = 256 B contiguous.
//   q = t>>6    -> 16-way u split  => thread reduces 256 u in registers.
//   x staged to LDS in 4 superchunks of 1024 u; broadcast reads (free).
//   epilogue: 16-way reduction via LDS, scaled by 1/sqrt(4096) = 1/64.

constexpr int MUL = 4096;
constexpr int VT  = 64;          // v per block
constexpr int NQ  = 16;          // u-split within block
constexpr int SC  = 4;           // LDS superchunks over u
constexpr int SCU = MUL / SC;    // 1024 u per superchunk
constexpr int UPT = SCU / NQ;    // 64 u per thread per superchunk

template<int D>
__device__ __forceinline__ void body(
    const float* __restrict__ w, const float* __restrict__ x,
    float* __restrict__ out, float* xs, float* red,
    int io_off, long w_off, int v0)
{
  const int t  = threadIdx.x;
  const int lv = t & 63;
  const int q  = t >> 6;
  const long wcol = w_off + v0 + lv;      // + u*4096 per step

  float acc[D];
  #pragma unroll
  for (int i = 0; i < D; ++i) acc[i] = 0.f;

  for (int c = 0; c < SC; ++c) {
    const int ub = c * SCU;
    __syncthreads();                       // protect xs from previous iter
    for (int j = t; j < SCU * D; j += 1024)
      xs[j] = x[io_off + ub * D + j];
    __syncthreads();

    const int u0 = q * UPT;
    #pragma unroll 8
    for (int uu = 0; uu < UPT; ++uu) {
      const int u = u0 + uu;               // u within superchunk
      float wv = w[wcol + (long)(ub + u) * MUL];
      #pragma unroll
      for (int i = 0; i < D; ++i)
        acc[i] = fmaf(wv, xs[u * D + i], acc[i]);
    }
  }

  // cross-q reduction through LDS
  #pragma unroll
  for (int i = 0; i < D; ++i)
    red[q * VT * D + lv * D + i] = acc[i];
  __syncthreads();

  for (int j = t; j < VT * D; j += 1024) {
    float s = 0.f;
    #pragma unroll
    for (int qq = 0; qq < NQ; ++qq) s += red[qq * VT * D + j];
    out[io_off + v0 * D + j] = s * 0.015625f;
  }
}

__global__ __launch_bounds__(1024)
void linear_all(const float* __restrict__ w, const float* __restrict__ x,
                float* __restrict__ out)
{
  __shared__ float xs [SCU * 7];       // 28 KiB
  __shared__ float red[NQ * VT * 7];   // 28 KiB
  const int b  = blockIdx.x;
  const int p  = b >> 6;               // 64 blocks per path
  const int v0 = (b & 63) * VT;

  if      (p == 0) body<1>(w, x, out, xs, red,     0,         0L, v0);
  else if (p == 1) body<3>(w, x, out, xs, red,  4096, 16777216L, v0);
  else if (p == 2) body<5>(w, x, out, xs, red, 16384, 33554432L, v0);
  else             body<7>(w, x, out, xs, red, 36864, 50331648L, v0);
}

extern "C" void kernel_launch(void* const* d_in, const int* in_sizes, int n_in,
                              void* d_out, int out_size, void* d_ws, size_t ws_size,
                              hipStream_t stream) {
  const float* x = (const float*)d_in[0];   // 65536 f32
  const float* w = (const float*)d_in[1];   // 67108864 f32
  linear_all<<<256, 1024, 0, stream>>>(w, x, (float*)d_out);
}

// Round 4
// 361.547 us; speedup vs baseline: 1.1667x; 1.1667x over previous
//
#include <hip/hip_runtime.h>
#include <stdint.h>

// irreps linear: 4 paths, out[v,i] = (1/64) * sum_u x[u,i] * w[u,v]
// mul = 4096 all paths, D in {1,3,5,7}. All tensors f32. No workspace.
//
// R3 -> R4: kernel was latency-bound (800 GB/s, VALUBusy 4.7%, ~2-3
// outstanding loads/wave). Fix: explicit 16-deep register prefetch batch
// so 16 global_load_dword are in flight per wave (64 KB/CU >> 22 KB
// needed by Little's law at 900 cyc).
//
//   grid = 256 blocks (= 4 paths x 64 v-tiles of 64), 1024 threads (16 waves).
//   lane (t&63) -> v within tile  => per-u wave load = 256 B contiguous.
//   q = t>>6    -> 16-way u split  => thread reduces 256 u in registers.
//   x staged to LDS in 4 superchunks of 1024 u; broadcast reads (free).
//   epilogue: 16-way reduction via LDS, scaled by 1/sqrt(4096) = 1/64.

constexpr int MUL = 4096;
constexpr int VT  = 64;          // v per block
constexpr int NQ  = 16;          // u-split within block
constexpr int SC  = 4;           // LDS superchunks over u
constexpr int SCU = MUL / SC;    // 1024 u per superchunk
constexpr int UPT = SCU / NQ;    // 64 u per thread per superchunk
constexpr int PF  = 16;          // prefetch depth (registers)

template<int D>
__device__ __forceinline__ void body(
    const float* __restrict__ w, const float* __restrict__ x,
    float* __restrict__ out, float* xs, float* red,
    int io_off, long w_off, int v0)
{
  const int t  = threadIdx.x;
  const int lv = t & 63;
  const int q  = t >> 6;
  const long wcol = w_off + v0 + lv;      // + u*4096 per step

  float acc[D];
  #pragma unroll
  for (int i = 0; i < D; ++i) acc[i] = 0.f;

  for (int c = 0; c < SC; ++c) {
    const int ub = c * SCU;
    __syncthreads();                       // protect xs from previous iter
    for (int j = t; j < SCU * D; j += 1024)
      xs[j] = x[io_off + ub * D + j];
    __syncthreads();

    const int u0 = q * UPT;
    for (int bb = 0; bb < UPT; bb += PF) {
      float wv[PF];
      #pragma unroll
      for (int j = 0; j < PF; ++j)         // PF independent loads in flight
        wv[j] = w[wcol + (long)(ub + u0 + bb + j) * MUL];
      #pragma unroll
      for (int j = 0; j < PF; ++j) {
        const float* xr = xs + (u0 + bb + j) * D;
        #pragma unroll
        for (int i = 0; i < D; ++i)
          acc[i] = fmaf(wv[j], xr[i], acc[i]);
      }
    }
  }

  // cross-q reduction through LDS
  #pragma unroll
  for (int i = 0; i < D; ++i)
    red[q * VT * D + lv * D + i] = acc[i];
  __syncthreads();

  for (int j = t; j < VT * D; j += 1024) {
    float s = 0.f;
    #pragma unroll
    for (int qq = 0; qq < NQ; ++qq) s += red[qq * VT * D + j];
    out[io_off + v0 * D + j] = s * 0.015625f;
  }
}

__global__ __launch_bounds__(1024)
void linear_all(const float* __restrict__ w, const float* __restrict__ x,
                float* __restrict__ out)
{
  __shared__ float xs [SCU * 7];       // 28 KiB
  __shared__ float red[NQ * VT * 7];   // 28 KiB
  const int b  = blockIdx.x;
  const int p  = b >> 6;               // 64 blocks per path
  const int v0 = (b & 63) * VT;

  if      (p == 0) body<1>(w, x, out, xs, red,     0,         0L, v0);
  else if (p == 1) body<3>(w, x, out, xs, red,  4096, 16777216L, v0);
  else if (p == 2) body<5>(w, x, out, xs, red, 16384, 33554432L, v0);
  else             body<7>(w, x, out, xs, red, 36864, 50331648L, v0);
}

extern "C" void kernel_launch(void* const* d_in, const int* in_sizes, int n_in,
                              void* d_out, int out_size, void* d_ws, size_t ws_size,
                              hipStream_t stream) {
  const float* x = (const float*)d_in[0];   // 65536 f32
  const float* w = (const float*)d_in[1];   // 67108864 f32
  linear_all<<<256, 1024, 0, stream>>>(w, x, (float*)d_out);
}